// Round 10
// baseline (322.481 us; speedup 1.0000x reference)
//
#include <hip/hip_runtime.h>

// Problem constants
#define CDIM 256        // token_size (channels)
#define CB   4096       // codebook size
#define HW   1024       // 32*32
#define NTOK 32768      // tokens
#define NELEM 8388608   // 32*256*32*32
#define MARGIN 3.5e-4f  // screen margin; worst-case need ~2e-4 (13-sigma bf16 tail)
#define OVCAP 64        // overflow slots/token; lambda~11.3 -> P(>64) ~ 0 (r12 lesson)

typedef float f32x4 __attribute__((ext_vector_type(4)));
typedef short bf16x8 __attribute__((ext_vector_type(8)));
typedef unsigned int u32;
typedef unsigned long long u64;

__device__ __forceinline__ unsigned short f2bf(float x) {   // RNE fp32->bf16
    u32 b = __float_as_uint(x);
    return (unsigned short)((b + 0x7fffu + ((b >> 16) & 1u)) >> 16);
}
// order-preserving float <-> uint
__device__ __forceinline__ u32 fenc(float f) {
    u32 b = __float_as_uint(f);
    return (b & 0x80000000u) ? ~b : (b | 0x80000000u);
}
__device__ __forceinline__ float fdec(u32 u) {
    return __uint_as_float((u & 0x80000000u) ? (u & 0x7fffffffu) : ~u);
}
__device__ __forceinline__ u64 shfl_xor_u64(u64 v, int s) {
    u32 lo = __shfl_xor((u32)v, s);
    u32 hi = __shfl_xor((u32)(v >> 32), s);
    return ((u64)hi << 32) | lo;
}
// async global->LDS, 16B per lane; lds dest = wave-uniform base + lane*16
__device__ __forceinline__ void gl_lds16(const void* g, void* l) {
    __builtin_amdgcn_global_load_lds(
        (const __attribute__((address_space(1))) u32*)g,
        (__attribute__((address_space(3))) u32*)l, 16, 0, 0);
}

// LESSONS: single-pass barrier-free epilogue, hot-path atomic-free, OVCAP 5x
// headroom, no single-address atomicAdd per wave, RE-CHECK LAUNCH DIMS AFTER
// ANY KERNEL RESHAPE (violated r2->r14, violated AGAIN r8).
// r0: dbuf + quad-swizzle fix (conflicts 8.4M->0) + 32x128 waves. 205->149us.
// r1: A direct global->VGPR (zero cross-wave reuse). 149->130us.
// r2 FAILED: 2 waves/SIMD occupancy loss. p1 is LATENCY/OCCUPANCY-bound.
// r3: counted vmcnt(2)+s_barrier + setprio. 130->121us. p1 K-loop FROZEN.
// r4: prep/k2 widened. 268.8->258. r5 FAILED (481us): fusion serialized the
//     latency-bound rescore. LESSON: latency-bound => MAX wave count.
// r6/r7: XCD swizzle: traffic 4x down but +2.3us (latency-bound; traffic is
//     free) -> stripped. census: +3us -> stripped. 262.2us @ r7.
// r8 CRASHED: diagnostic split had grid 2048 x 8 launches = 64 cg values
//     (only 32 exist) -> OOB e_hip/enorm2 reads + cross-token cand writes.
// THIS ROUND (r9): same diagnostic, dims RE-DERIVED: 8 launches x grid 1024
//     (256 rg x 4 cg; rg=bid>>2, cg=cg0+(bid&3), cg0=i*4; each (rg,cg) once;
//     cg<=31, e_hip off <=31<<16 <2MB, cand slot <=31 — all bounds checked).
//     Each sub ~16us -> top-5 MUST surface the slowest of prep/k5/k2 with
//     full counters. Next round acts on that row and re-merges p1.

// ---------------- prep: 512 blocks x 1024 threads; p0 + folded k0e ----------------
__global__ __launch_bounds__(1024) void prep(const float* __restrict__ z,
                                             const float* __restrict__ emb,
                                             float* __restrict__ zT,
                                             unsigned short* __restrict__ z_hip,
                                             float* __restrict__ zn,
                                             u32* __restrict__ ovcnt,
                                             float* __restrict__ enorm2,
                                             unsigned short* __restrict__ e_hip,
                                             u32* __restrict__ cnt2) {
    __shared__ float T[128][64];               // 32 KB -> 2 blocks/CU, 100% occ
    const int tid = threadIdx.x;
    const int tg = blockIdx.x;                 // 64-token group, grid = 512
    // ---- folded k0e: 8 codes/block by threads 0..15 (no sync dependency) ----
    // (2 threads/code, linear 128-ch halves; summation order is part of the
    //  reference rounding chain — do not reorder.)
    if (tid < 16) {
        const int code = tg * 8 + (tid >> 1);
        const int cl = code & 127;             // index within 128-code col-group
        const int cgE = code >> 7;
        const int sxzE = (cl >> 1) & 3;        // swizzle key (bank fix, r0)
        float s = 0.f;
#pragma unroll
        for (int kb = 0; kb < 4; ++kb) {
            const int c0 = (tid & 1) * 128 + kb * 32;
            const int kc = c0 >> 5;
            __align__(16) unsigned short tmp[32];
#pragma unroll
            for (int q = 0; q < 8; ++q) {
                float4 v = *(const float4*)(emb + (size_t)code * CDIM + c0 + 4 * q);
                s += v.x * v.x + v.y * v.y + v.z * v.z + v.w * v.w;
                tmp[4 * q + 0] = f2bf(v.x); tmp[4 * q + 1] = f2bf(v.y);
                tmp[4 * q + 2] = f2bf(v.z); tmp[4 * q + 3] = f2bf(v.w);
            }
            uint4* dst4 = (uint4*)(e_hip + (((size_t)(cgE * 8 + kc) * 128 + cl) * 32));
#pragma unroll
            for (int q = 0; q < 4; ++q)
                dst4[q ^ sxzE] = *(uint4*)&tmp[8 * q];   // XOR-swizzled quads
        }
        s += __shfl_xor(s, 1);
        if ((tid & 1) == 0) enorm2[code] = s;
        if (tg == 0 && tid == 0) *cnt2 = 0u;   // k2 last-block election counter
    }
    // ---- p0 role: transpose z -> zT fp32 + packed/swizzled bf16 z + zn/ovcnt ----
    const int b = tg >> 4, hw0 = (tg * 64) & 1023;
    const float* zb = z + (size_t)b * (CDIM * HW) + hw0;
    const int tt = tid & 63;                   // token within group
    const int qrole = tid >> 6;                // 0..15: one 8-chan quad per grp
    const int kcl = qrole >> 2;                // kc chunk within 128-ch grp (0..3)
    const int qq = qrole & 3;                  // quad within chunk
    const int gz = tg >> 1;                    // 128-token pack group
    const int rowl = (tg & 1) * 64 + tt;       // row within pack group
    const int sxz = (tt >> 1) & 3;             // swizzle key ((rowl>>1)&3 == this)
    float zacc = 0.f;                          // zn order free: translation-invariant
#pragma unroll
    for (int grp = 0; grp < 2; ++grp) {
        const int c0 = grp * 128;
        __syncthreads();                       // T free (prev pack readers done)
#pragma unroll
        for (int p = 0; p < 8; ++p) {          // wave-coalesced 256B rows
            const int c = p * 16 + qrole;
            T[c][tt] = zb[(size_t)(c0 + c) * HW + tt];
        }
        __syncthreads();
        const int kc = grp * 4 + kcl;
        const int cb = kcl * 32 + qq * 8;      // channel base within grp
        float* dstT = zT + (size_t)(tg * 64 + tt) * CDIM + c0 + cb;
        __align__(16) unsigned short us[8];
#pragma unroll
        for (int q = 0; q < 2; ++q) {
            float4 v;
            v.x = T[cb + 4 * q + 0][tt]; v.y = T[cb + 4 * q + 1][tt];
            v.z = T[cb + 4 * q + 2][tt]; v.w = T[cb + 4 * q + 3][tt];
            ((float4*)dstT)[q] = v;
            zacc += v.x * v.x + v.y * v.y + v.z * v.z + v.w * v.w;
            us[4 * q + 0] = f2bf(v.x); us[4 * q + 1] = f2bf(v.y);
            us[4 * q + 2] = f2bf(v.z); us[4 * q + 3] = f2bf(v.w);
        }
        uint4* d4 = (uint4*)(z_hip + (((size_t)(gz * 8 + kc) * 128 + rowl) * 32));
        d4[qq ^ sxz] = *(uint4*)&us[0];        // XOR-swizzled quad
    }
    // ---- zn: reduce 16 role-partials per token via T-overlay ----
    __syncthreads();                           // pack reads of T done
    float* zp = &T[0][0];
    zp[qrole * 64 + tt] = zacc;
    __syncthreads();
    if (tid < 64) {
        float s = 0.f;
#pragma unroll
        for (int r = 0; r < 16; ++r) s += zp[r * 64 + tid];
        zn[tg * 64 + tid] = s;
        ovcnt[tg * 64 + tid] = 0u;
    }
}

// Tile: 128 tokens x 128 codes, K=256 in 8 chunks of 32; B double-buffered in
// LDS (16KB), A DIRECT global->VGPR (zero cross-wave reuse -> no LDS round-trip).
// 4 waves; wave w owns rows [w*32, w*32+32) x all 128 cols -> acc[2][8].
// A[m=lane&15][k=quad*8+j]; B as B^T rows (n=lane&15); C: col=lane&15,
// row=quad*4+reg (m89-verified).
// r9 DIAGNOSTIC split: each launch covers 4 cg's (grid 1024 = 256 rg x 4 cg);
// rg = bid>>2, cg = cg0 + (bid&3), cg0 = i*4, i=0..7. Bounds re-derived.

// ---------------- p1: bf16 MFMA screen -> per-(token, col-group) min slot + rare overflow ----
__global__ __launch_bounds__(256, 4) void p1(const unsigned short* __restrict__ z_hip,
                                             const unsigned short* __restrict__ e_hip,
                                             const float* __restrict__ enorm2,
                                             u64* __restrict__ cand,
                                             u32* __restrict__ ovcnt,
                                             u64* __restrict__ ovslot,
                                             int cg0) {
    __shared__ __align__(16) unsigned short Bs[2][128 * 32];
    const int bid = blockIdx.x;                // grid = 1024 per sub-launch
    const int rg = bid >> 2;                   // 0..255; consecutive blocks share A-rows
    const int cg = cg0 + (bid & 3);            // 0..31 across the 8 sub-launches
    const int tid = threadIdx.x;
    const int w = tid >> 6, lane = tid & 63;
    const int quad = lane >> 4, l15 = lane & 15;
    const int swz = (quad ^ ((l15 >> 1) & 3)) * 8;  // de-swizzle (bank-conflict-free)

    f32x4 acc[2][8];
#pragma unroll
    for (int i = 0; i < 2; ++i)
#pragma unroll
        for (int j = 0; j < 8; ++j)
#pragma unroll
            for (int e = 0; e < 4; ++e) acc[i][j][e] = 0.f;

    const char* gB = (const char*)e_hip + ((size_t)cg << 16) + w * 2048 + lane * 16;
    // A direct-to-reg: per-lane fragment address; same swizzle algebra as the
    // packed store ((row>>1)&3 == (l15>>1)&3 for row = w*32 + mi*16 + l15).
    const char* gA0 = (const char*)z_hip + ((size_t)rg << 16)
                      + (w * 32 + l15) * 64 + swz * 2;
    char* lB = (char*)Bs + w * 2048;           // wave-uniform LDS base (buffer 0)
    // prologue: stage B kc=0, load A frags kc=0
    gl_lds16(gB, lB);           gl_lds16(gB + 1024, lB + 1024);
    gB += 8192;
    bf16x8 af0 = *(const bf16x8*)(gA0);
    bf16x8 af1 = *(const bf16x8*)(gA0 + 1024);
    __syncthreads();                           // full drain before first use
#pragma unroll
    for (int kc = 0; kc < 8; ++kc) {
        const int cur = kc & 1;
        bf16x8 afn0, afn1;
        if (kc < 7) {                          // stage next B tile into other buffer
            char* dB = lB + (cur ^ 1) * 8192;
            gl_lds16(gB, dB);       gl_lds16(gB + 1024, dB + 1024);
            gB += 8192;
            asm volatile("" ::: "memory");     // pin: B-stages are the OLDEST vmem ops
            // prefetch next A fragments (global->reg, stay in flight past barrier)
            const char* gA = gA0 + (size_t)(kc + 1) * 8192;
            afn0 = *(const bf16x8*)(gA);
            afn1 = *(const bf16x8*)(gA + 1024);
        }
        const unsigned short* B0 = Bs[cur];
        __builtin_amdgcn_s_setprio(1);         // T5: favor MFMA-issuing wave
#pragma unroll
        for (int nh = 0; nh < 2; ++nh) {       // 4-at-a-time B frags (VGPR cap)
            bf16x8 bfr[4];
#pragma unroll
            for (int nj = 0; nj < 4; ++nj)
                bfr[nj] = *(const bf16x8*)&B0[((nh * 4 + nj) * 16 + l15) * 32 + swz];
#pragma unroll
            for (int nj = 0; nj < 4; ++nj) {
                acc[0][nh * 4 + nj] = __builtin_amdgcn_mfma_f32_16x16x32_bf16(
                    af0, bfr[nj], acc[0][nh * 4 + nj], 0, 0, 0);
                acc[1][nh * 4 + nj] = __builtin_amdgcn_mfma_f32_16x16x32_bf16(
                    af1, bfr[nj], acc[1][nh * 4 + nj], 0, 0, 0);
            }
        }
        __builtin_amdgcn_s_setprio(0);
        if (kc < 7) {
            af0 = afn0; af1 = afn1;
            // counted wait: retire the 2 B-stages (oldest); A loads stay in flight
            asm volatile("s_waitcnt vmcnt(2)" ::: "memory");
            __builtin_amdgcn_s_barrier();
            asm volatile("" ::: "memory");     // pin next-kc ds_reads below barrier
        }
    }
    // ---- single-pass, barrier-free epilogue (float butterfly + ballot election) ----
    float en[8];
#pragma unroll
    for (int ni = 0; ni < 8; ++ni) en[ni] = enorm2[cg * 128 + ni * 16 + l15];
#pragma unroll
    for (int mi = 0; mi < 2; ++mi) {
#pragma unroll
        for (int r = 0; r < 4; ++r) {
            const int row = w * 32 + mi * 16 + quad * 4 + r;
            const int t = rg * 128 + row;
            float dv[8];
#pragma unroll
            for (int ni = 0; ni < 8; ++ni) dv[ni] = en[ni] - 2.0f * acc[mi][ni][r];
            float m = fminf(fminf(fminf(dv[0], dv[1]), fminf(dv[2], dv[3])),
                            fminf(fminf(dv[4], dv[5]), fminf(dv[6], dv[7])));
            m = fminf(m, __shfl_xor(m, 1));
            m = fminf(m, __shfl_xor(m, 2));
            m = fminf(m, __shfl_xor(m, 4));
            m = fminf(m, __shfl_xor(m, 8));        // 16-lane group min (exact bits)
            u32 myni = 8u;
#pragma unroll
            for (int ni = 7; ni >= 0; --ni)
                if (dv[ni] == m) myni = (u32)ni;   // lowest matching ni
            const unsigned long long bal = __ballot(myni < 8u);
            const int sl = __ffs((u32)((bal >> (quad << 4)) & 0xFFFFu)) - 1;
            if (l15 == sl) {                        // elected lane stores the slot
                const u32 k = (u32)(cg * 128 + (int)myni * 16 + l15);
                cand[((size_t)t << 5) + cg] = ((u64)fenc(m) << 32) | k;
            }
            const float thr = m + MARGIN;
#pragma unroll
            for (int ni = 0; ni < 8; ++ni) {        // rare-path extras (execz-cheap)
                if (dv[ni] <= thr && !(l15 == sl && ni == (int)myni)) {
                    const u32 k = (u32)(cg * 128 + ni * 16 + l15);
                    const u32 pos = atomicAdd(&ovcnt[t], 1u);
                    if (pos < (u32)OVCAP)
                        ovslot[(size_t)t * OVCAP + pos] = ((u64)fenc(dv[ni]) << 32) | k;
                }
            }
        }
    }
}

// ---------------- k5: gmin from 32 slots, filter, exact fp32 rescore; dmin via plain store ----
// 1 wave per token (32768 waves) — latency-bound phase at MAX parallelism (r5 lesson).
__global__ __launch_bounds__(256) void k5(const float* __restrict__ zT,
                                          const float* __restrict__ emb,
                                          const float* __restrict__ enorm2,
                                          const float* __restrict__ zn,
                                          const u64* __restrict__ cand,
                                          const u32* __restrict__ ovcnt,
                                          const u64* __restrict__ ovslot,
                                          float* __restrict__ idxf,
                                          float* __restrict__ dmin) {
    const int t = (blockIdx.x * 256 + threadIdx.x) >> 6;   // wave per token, grid = 8192
    const int lane = threadIdx.x & 63;
    const u64 pkv = cand[((size_t)t << 5) + (lane & 31)];  // 32 slots, dup across halves
    u64 g = pkv;
#pragma unroll
    for (int s = 1; s < 32; s <<= 1) {                     // 5-step min within each half
        const u64 o = shfl_xor_u64(g, s);
        g = o < g ? o : g;
    }
    const float thr = fdec((u32)(g >> 32)) + MARGIN;       // gmin + MARGIN
    const float4 za = ((const float4*)(zT + (size_t)t * CDIM))[lane];
    const float znv = zn[t];
    float bdv = 1e30f; int bk = 0x7fffffff;
    unsigned long long q = __ballot(fdec((u32)(pkv >> 32)) <= thr)
                           & 0xFFFFFFFFull;                // low half only (no dups)
    while (q) {
        const int i = __ffsll(q) - 1; q &= q - 1;
        const int k = __shfl((int)(u32)pkv, i);
        const float4 ea = ((const float4*)(emb + (size_t)k * CDIM))[lane];
        float p = za.x * ea.x + za.y * ea.y + za.z * ea.z + za.w * ea.w;
#pragma unroll
        for (int s = 1; s < 64; s <<= 1) p += __shfl_xor(p, s);
        const float t1 = znv + enorm2[k];         // fl(zn + en)  — reference chain
        const float d = t1 - 2.0f * p;            // fl(t1 - 2 dot)
        if (d < bdv || (d == bdv && k < bk)) { bdv = d; bk = k; }
    }
    u32 n = ovcnt[t]; if (n > (u32)OVCAP) n = (u32)OVCAP;  // overflow survivors (rare)
    for (u32 i = 0; i < n; ++i) {
        const u64 ov = ovslot[(size_t)t * OVCAP + i];      // wave-uniform broadcast load
        if (!(fdec((u32)(ov >> 32)) <= thr)) continue;
        const int k = (int)(u32)ov;
        const float4 ea = ((const float4*)(emb + (size_t)k * CDIM))[lane];
        float p = za.x * ea.x + za.y * ea.y + za.z * ea.z + za.w * ea.w;
#pragma unroll
        for (int s = 1; s < 64; s <<= 1) p += __shfl_xor(p, s);
        const float t1 = znv + enorm2[k];
        const float d = t1 - 2.0f * p;
        if (d < bdv || (d == bdv && k < bk)) { bdv = d; bk = k; }
    }
    if (lane == 0) {
        idxf[t] = (float)bk;
        dmin[t] = bdv;        // plain coalesced store (NO atomics — r13 lesson)
    }
}

// ---------------- k2: scatter z_q = emb[idx]; last block reduces dmin -> loss scalars ----------
// 1024 threads (100% occupancy at 2 blocks/CU); same per-wave access pattern.
__global__ __launch_bounds__(1024) void k2(const float* __restrict__ emb,
                                           const float* __restrict__ idxf,
                                           const float* __restrict__ dmin,
                                           float* __restrict__ zq,
                                           float* __restrict__ out3,
                                           u32* __restrict__ cnt2) {
    __shared__ int ks[64];
    __shared__ float red[1024];
    __shared__ int lastFlag;
    const int tid = threadIdx.x;
    const int tok0 = blockIdx.x * 64;          // grid = 512
    const int b = tok0 >> 10, hw0 = tok0 & 1023;
    if (tid < 64) ks[tid] = (int)idxf[tok0 + tid];
    __syncthreads();
    const int t4 = (tid & 15) * 4;
    const int ka = ks[t4], kb = ks[t4 + 1], kc = ks[t4 + 2], kd = ks[t4 + 3];
    float* outb = zq + (size_t)b * (CDIM * HW) + hw0 + t4;
    int c = tid >> 4;                          // 0..63
#pragma unroll
    for (int p = 0; p < 4; ++p, c += 64) {
        float4 v;
        v.x = emb[(size_t)ka * CDIM + c];
        v.y = emb[(size_t)kb * CDIM + c];
        v.z = emb[(size_t)kc * CDIM + c];
        v.w = emb[(size_t)kd * CDIM + c];
        *(float4*)(outb + (size_t)c * HW) = v;   // coalesced float4 store
    }
    // last-block election computes the loss (dmin complete: k5 precedes in stream)
    if (tid == 0) lastFlag = (atomicAdd(cnt2, 1u) == 511u) ? 1 : 0;
    __syncthreads();
    if (lastFlag) {
        const float4* d4 = (const float4*)dmin;
        float s = 0.f;
        for (int i = tid; i < NTOK / 4; i += 1024) {
            const float4 v = d4[i];
            s += (v.x + v.y) + (v.z + v.w);
        }
        red[tid] = s;
        __syncthreads();
        for (int o = 512; o > 0; o >>= 1) {
            if (tid < o) red[tid] += red[tid + o];
            __syncthreads();
        }
        if (tid == 0) {
            const float mse = red[0] / (float)NELEM;
            out3[0] = 1.25f * mse;   // loss
            out3[1] = 0.25f * mse;   // commitment_loss
            out3[2] = mse;           // codebook_loss
        }
    }
}

extern "C" void kernel_launch(void* const* d_in, const int* in_sizes, int n_in,
                              void* d_out, int out_size, void* d_ws, size_t ws_size,
                              hipStream_t stream) {
    const float* z   = (const float*)d_in[0];   // [32,256,32,32]
    const float* emb = (const float*)d_in[1];   // [4096,256]
    float* out = (float*)d_out;                 // zq | 3 scalars | idx (as f32)
    char* w = (char*)d_ws;

    float* zn     = (float*)w;                       w += NTOK * 4;
    float* enorm2 = (float*)w;                       w += CB * 4;
    u32*   ovcnt  = (u32*)w;                         w += NTOK * 4;
    float* dmin   = (float*)w;                       w += NTOK * 4;
    u32*   cnt2   = (u32*)w;                         w += 256;
    float* zT     = (float*)w;                       w += (size_t)NTOK * CDIM * 4;
    unsigned short* z_hip = (unsigned short*)w;      w += (size_t)NTOK * CDIM * 2;
    unsigned short* e_hip = (unsigned short*)w;      w += (size_t)CB * CDIM * 2;
    u64*   cand   = (u64*)w;                         w += (size_t)NTOK * 32 * 8;
    u64*   ovslot = (u64*)w;                         w += (size_t)NTOK * OVCAP * 8;
    float* idxf = out + NELEM + 3;

    hipLaunchKernelGGL(prep, dim3(512),       dim3(1024), 0, stream,
                       z, emb, zT, z_hip, zn, ovcnt, enorm2, e_hip, cnt2);
    for (int i = 0; i < 8; ++i)                // r9 DIAGNOSTIC: 8 x (256 rg x 4 cg)
        hipLaunchKernelGGL(p1, dim3(1024), dim3(256), 0, stream,
                           z_hip, e_hip, enorm2, cand, ovcnt, ovslot, i * 4);
    hipLaunchKernelGGL(k5,  dim3(NTOK / 4),   dim3(256), 0, stream,
                       zT, emb, enorm2, zn, cand, ovcnt, ovslot, idxf, dmin);
    hipLaunchKernelGGL(k2,  dim3(NTOK / 64),  dim3(1024), 0, stream,
                       emb, idxf, dmin, out, out + NELEM, cnt2);
}

// Round 11
// 299.578 us; speedup vs baseline: 1.0765x; 1.0765x over previous
//
#include <hip/hip_runtime.h>

// Problem constants
#define CDIM 256        // token_size (channels)
#define CB   4096       // codebook size
#define HW   1024       // 32*32
#define NTOK 32768      // tokens
#define NELEM 8388608   // 32*256*32*32
#define MARGIN 3.5e-4f  // screen margin; worst-case need ~2e-4 (13-sigma bf16 tail)
#define OVCAP 64        // overflow slots/token; lambda~11.3 -> P(>64) ~ 0 (r12 lesson)

typedef float f32x4 __attribute__((ext_vector_type(4)));
typedef short bf16x8 __attribute__((ext_vector_type(8)));
typedef unsigned int u32;
typedef unsigned long long u64;

__device__ __forceinline__ unsigned short f2bf(float x) {   // RNE fp32->bf16
    u32 b = __float_as_uint(x);
    return (unsigned short)((b + 0x7fffu + ((b >> 16) & 1u)) >> 16);
}
// order-preserving float <-> uint
__device__ __forceinline__ u32 fenc(float f) {
    u32 b = __float_as_uint(f);
    return (b & 0x80000000u) ? ~b : (b | 0x80000000u);
}
__device__ __forceinline__ float fdec(u32 u) {
    return __uint_as_float((u & 0x80000000u) ? (u & 0x7fffffffu) : ~u);
}
__device__ __forceinline__ u64 shfl_xor_u64(u64 v, int s) {
    u32 lo = __shfl_xor((u32)v, s);
    u32 hi = __shfl_xor((u32)(v >> 32), s);
    return ((u64)hi << 32) | lo;
}

// LESSONS: single-pass barrier-free epilogue, hot-path atomic-free, OVCAP 5x
// headroom, no single-address atomicAdd per wave, RE-CHECK LAUNCH DIMS AFTER
// ANY KERNEL RESHAPE (r8 crash). Latency-bound phases need MAX wave count (r5).
// Never bundle >1 unverified change (r5/r6).
// r0-r3: p1 ladder 205->121us (dbuf, A-direct, counted vmcnt, setprio).
// r4/r7: prep/k2 widened -> small effect. r6: XCD swizzle traffic-confirmed
//     (4x less) but time-neutral (latency-bound) -> stripped.
// r9 DIAGNOSTIC FINDING: with p1 split ~16us, top-5 = harness fillBuffer
//     (256MiB @ 6.3TB/s, 42-43us each) — prep/k5/k2 are EACH <41.5us. The
//     "137us non-p1 mystery" was largely harness workspace re-poison fills
//     (uncontrollable) + launch gaps. p1 is the only big lever we own.
// THIS ROUND (r10): p1 re-merged AND made BARRIER-FREE: B fragments load
//     global->VGPR directly (Bs was an identity copy of the e_hip chunk; a
//     wave's 64 lanes cover a contiguous, perfectly-coalesced 1KB per frag;
//     2MB codebook is L2-resident). Deletes all LDS/ds_read/gl_lds16/
//     __syncthreads from p1: DS-pipe K-loop ->0, LDS 16KB->0, residency
//     4 blocks/CU (VGPR-capped 120<=128). Waves free-run.

// ---------------- prep: 512 blocks x 1024 threads; p0 + folded k0e ----------------
__global__ __launch_bounds__(1024) void prep(const float* __restrict__ z,
                                             const float* __restrict__ emb,
                                             float* __restrict__ zT,
                                             unsigned short* __restrict__ z_hip,
                                             float* __restrict__ zn,
                                             u32* __restrict__ ovcnt,
                                             float* __restrict__ enorm2,
                                             unsigned short* __restrict__ e_hip,
                                             u32* __restrict__ cnt2) {
    __shared__ float T[128][64];               // 32 KB -> 2 blocks/CU, 100% occ
    const int tid = threadIdx.x;
    const int tg = blockIdx.x;                 // 64-token group, grid = 512
    // ---- folded k0e: 8 codes/block by threads 0..15 (no sync dependency) ----
    // (2 threads/code, linear 128-ch halves; summation order is part of the
    //  reference rounding chain — do not reorder.)
    if (tid < 16) {
        const int code = tg * 8 + (tid >> 1);
        const int cl = code & 127;             // index within 128-code col-group
        const int cgE = code >> 7;
        const int sxzE = (cl >> 1) & 3;        // swizzle key (bank fix, r0)
        float s = 0.f;
#pragma unroll
        for (int kb = 0; kb < 4; ++kb) {
            const int c0 = (tid & 1) * 128 + kb * 32;
            const int kc = c0 >> 5;
            __align__(16) unsigned short tmp[32];
#pragma unroll
            for (int q = 0; q < 8; ++q) {
                float4 v = *(const float4*)(emb + (size_t)code * CDIM + c0 + 4 * q);
                s += v.x * v.x + v.y * v.y + v.z * v.z + v.w * v.w;
                tmp[4 * q + 0] = f2bf(v.x); tmp[4 * q + 1] = f2bf(v.y);
                tmp[4 * q + 2] = f2bf(v.z); tmp[4 * q + 3] = f2bf(v.w);
            }
            uint4* dst4 = (uint4*)(e_hip + (((size_t)(cgE * 8 + kc) * 128 + cl) * 32));
#pragma unroll
            for (int q = 0; q < 4; ++q)
                dst4[q ^ sxzE] = *(uint4*)&tmp[8 * q];   // XOR-swizzled quads
        }
        s += __shfl_xor(s, 1);
        if ((tid & 1) == 0) enorm2[code] = s;
        if (tg == 0 && tid == 0) *cnt2 = 0u;   // k2 last-block election counter
    }
    // ---- p0 role: transpose z -> zT fp32 + packed/swizzled bf16 z + zn/ovcnt ----
    const int b = tg >> 4, hw0 = (tg * 64) & 1023;
    const float* zb = z + (size_t)b * (CDIM * HW) + hw0;
    const int tt = tid & 63;                   // token within group
    const int qrole = tid >> 6;                // 0..15: one 8-chan quad per grp
    const int kcl = qrole >> 2;                // kc chunk within 128-ch grp (0..3)
    const int qq = qrole & 3;                  // quad within chunk
    const int gz = tg >> 1;                    // 128-token pack group
    const int rowl = (tg & 1) * 64 + tt;       // row within pack group
    const int sxz = (tt >> 1) & 3;             // swizzle key ((rowl>>1)&3 == this)
    float zacc = 0.f;                          // zn order free: translation-invariant
#pragma unroll
    for (int grp = 0; grp < 2; ++grp) {
        const int c0 = grp * 128;
        __syncthreads();                       // T free (prev pack readers done)
#pragma unroll
        for (int p = 0; p < 8; ++p) {          // wave-coalesced 256B rows
            const int c = p * 16 + qrole;
            T[c][tt] = zb[(size_t)(c0 + c) * HW + tt];
        }
        __syncthreads();
        const int kc = grp * 4 + kcl;
        const int cb = kcl * 32 + qq * 8;      // channel base within grp
        float* dstT = zT + (size_t)(tg * 64 + tt) * CDIM + c0 + cb;
        __align__(16) unsigned short us[8];
#pragma unroll
        for (int q = 0; q < 2; ++q) {
            float4 v;
            v.x = T[cb + 4 * q + 0][tt]; v.y = T[cb + 4 * q + 1][tt];
            v.z = T[cb + 4 * q + 2][tt]; v.w = T[cb + 4 * q + 3][tt];
            ((float4*)dstT)[q] = v;
            zacc += v.x * v.x + v.y * v.y + v.z * v.z + v.w * v.w;
            us[4 * q + 0] = f2bf(v.x); us[4 * q + 1] = f2bf(v.y);
            us[4 * q + 2] = f2bf(v.z); us[4 * q + 3] = f2bf(v.w);
        }
        uint4* d4 = (uint4*)(z_hip + (((size_t)(gz * 8 + kc) * 128 + rowl) * 32));
        d4[qq ^ sxz] = *(uint4*)&us[0];        // XOR-swizzled quad
    }
    // ---- zn: reduce 16 role-partials per token via T-overlay ----
    __syncthreads();                           // pack reads of T done
    float* zp = &T[0][0];
    zp[qrole * 64 + tt] = zacc;
    __syncthreads();
    if (tid < 64) {
        float s = 0.f;
#pragma unroll
        for (int r = 0; r < 16; ++r) s += zp[r * 64 + tid];
        zn[tg * 64 + tid] = s;
        ovcnt[tg * 64 + tid] = 0u;
    }
}

// Tile: 128 tokens x 128 codes, K=256 in 8 chunks of 32. NO LDS, NO BARRIERS:
// A and B fragments both load global->VGPR (B chunk in e_hip is the exact
// linear image the old LDS held; per (kc,ni) a wave covers a contiguous 1KB).
// 4 free-running waves; wave w owns rows [w*32,+32) x all 128 cols -> acc[2][8].
// A[m=lane&15][k=quad*8+j]; B as B^T rows (n=lane&15); C: col=lane&15,
// row=quad*4+reg (m89-verified).

// ---------------- p1: bf16 MFMA screen -> per-(token, col-group) min slot + rare overflow ----
// Epilogue: per row, float min over 8 ni + 4-step float butterfly; ballot elects
// lowest-l15 matching lane, which alone builds the u64 (d,k) slot pack. Ties/extras
// d<=min+MARGIN go to the overflow pool (duplicates harmless; k5 rescores).
__global__ __launch_bounds__(256, 4) void p1(const unsigned short* __restrict__ z_hip,
                                             const unsigned short* __restrict__ e_hip,
                                             const float* __restrict__ enorm2,
                                             u64* __restrict__ cand,
                                             u32* __restrict__ ovcnt,
                                             u64* __restrict__ ovslot) {
    const int bid = blockIdx.x;                // grid = 8192
    const int rg = bid >> 5, cg = bid & 31;    // consecutive blocks share A-rows (L2)
    const int tid = threadIdx.x;
    const int w = tid >> 6, lane = tid & 63;
    const int quad = lane >> 4, l15 = lane & 15;
    const int swz = (quad ^ ((l15 >> 1) & 3)) * 8;  // de-swizzle (coalesced-perm reads)

    f32x4 acc[2][8];
#pragma unroll
    for (int i = 0; i < 2; ++i)
#pragma unroll
        for (int j = 0; j < 8; ++j)
#pragma unroll
            for (int e = 0; e < 4; ++e) acc[i][j][e] = 0.f;

    // A direct-to-reg (r1): per-lane fragment address; swizzle algebra matches
    // the packed store ((row>>1)&3 == (l15>>1)&3 for row = w*32 + mi*16 + l15).
    const char* gA0 = (const char*)z_hip + ((size_t)rg << 16)
                      + (w * 32 + l15) * 64 + swz * 2;
    // B direct-to-reg (r10): frag (kc,ni) lives at gB0 + kc*8192 + ni*1024;
    // wave covers that contiguous 1KB exactly (l15*64B x 16B quad-perm).
    const char* gB0 = (const char*)e_hip + ((size_t)cg << 16) + l15 * 64 + swz * 2;

#pragma unroll
    for (int kc = 0; kc < 8; ++kc) {
        const char* gA = gA0 + kc * 8192;
        const char* gB = gB0 + kc * 8192;
        bf16x8 af0 = *(const bf16x8*)(gA);
        bf16x8 af1 = *(const bf16x8*)(gA + 1024);
#pragma unroll
        for (int nh = 0; nh < 2; ++nh) {       // 4-at-a-time B frags (VGPR cap)
            bf16x8 bfr[4];
#pragma unroll
            for (int nj = 0; nj < 4; ++nj)
                bfr[nj] = *(const bf16x8*)(gB + (nh * 4 + nj) * 1024);
#pragma unroll
            for (int nj = 0; nj < 4; ++nj) {
                acc[0][nh * 4 + nj] = __builtin_amdgcn_mfma_f32_16x16x32_bf16(
                    af0, bfr[nj], acc[0][nh * 4 + nj], 0, 0, 0);
                acc[1][nh * 4 + nj] = __builtin_amdgcn_mfma_f32_16x16x32_bf16(
                    af1, bfr[nj], acc[1][nh * 4 + nj], 0, 0, 0);
            }
        }
    }
    // ---- single-pass, barrier-free epilogue (float butterfly + ballot election) ----
    float en[8];
#pragma unroll
    for (int ni = 0; ni < 8; ++ni) en[ni] = enorm2[cg * 128 + ni * 16 + l15];
#pragma unroll
    for (int mi = 0; mi < 2; ++mi) {
#pragma unroll
        for (int r = 0; r < 4; ++r) {
            const int row = w * 32 + mi * 16 + quad * 4 + r;
            const int t = rg * 128 + row;
            float dv[8];
#pragma unroll
            for (int ni = 0; ni < 8; ++ni) dv[ni] = en[ni] - 2.0f * acc[mi][ni][r];
            float m = fminf(fminf(fminf(dv[0], dv[1]), fminf(dv[2], dv[3])),
                            fminf(fminf(dv[4], dv[5]), fminf(dv[6], dv[7])));
            m = fminf(m, __shfl_xor(m, 1));
            m = fminf(m, __shfl_xor(m, 2));
            m = fminf(m, __shfl_xor(m, 4));
            m = fminf(m, __shfl_xor(m, 8));        // 16-lane group min (exact bits)
            u32 myni = 8u;
#pragma unroll
            for (int ni = 7; ni >= 0; --ni)
                if (dv[ni] == m) myni = (u32)ni;   // lowest matching ni
            const unsigned long long bal = __ballot(myni < 8u);
            const int sl = __ffs((u32)((bal >> (quad << 4)) & 0xFFFFu)) - 1;
            if (l15 == sl) {                        // elected lane stores the slot
                const u32 k = (u32)(cg * 128 + (int)myni * 16 + l15);
                cand[((size_t)t << 5) + cg] = ((u64)fenc(m) << 32) | k;
            }
            const float thr = m + MARGIN;
#pragma unroll
            for (int ni = 0; ni < 8; ++ni) {        // rare-path extras (execz-cheap)
                if (dv[ni] <= thr && !(l15 == sl && ni == (int)myni)) {
                    const u32 k = (u32)(cg * 128 + ni * 16 + l15);
                    const u32 pos = atomicAdd(&ovcnt[t], 1u);
                    if (pos < (u32)OVCAP)
                        ovslot[(size_t)t * OVCAP + pos] = ((u64)fenc(dv[ni]) << 32) | k;
                }
            }
        }
    }
}

// ---------------- k5: gmin from 32 slots, filter, exact fp32 rescore; dmin via plain store ----
// 1 wave per token (32768 waves) — latency-bound phase at MAX parallelism (r5 lesson).
__global__ __launch_bounds__(256) void k5(const float* __restrict__ zT,
                                          const float* __restrict__ emb,
                                          const float* __restrict__ enorm2,
                                          const float* __restrict__ zn,
                                          const u64* __restrict__ cand,
                                          const u32* __restrict__ ovcnt,
                                          const u64* __restrict__ ovslot,
                                          float* __restrict__ idxf,
                                          float* __restrict__ dmin) {
    const int t = (blockIdx.x * 256 + threadIdx.x) >> 6;   // wave per token, grid = 8192
    const int lane = threadIdx.x & 63;
    const u64 pkv = cand[((size_t)t << 5) + (lane & 31)];  // 32 slots, dup across halves
    u64 g = pkv;
#pragma unroll
    for (int s = 1; s < 32; s <<= 1) {                     // 5-step min within each half
        const u64 o = shfl_xor_u64(g, s);
        g = o < g ? o : g;
    }
    const float thr = fdec((u32)(g >> 32)) + MARGIN;       // gmin + MARGIN
    const float4 za = ((const float4*)(zT + (size_t)t * CDIM))[lane];
    const float znv = zn[t];
    float bdv = 1e30f; int bk = 0x7fffffff;
    unsigned long long q = __ballot(fdec((u32)(pkv >> 32)) <= thr)
                           & 0xFFFFFFFFull;                // low half only (no dups)
    while (q) {
        const int i = __ffsll(q) - 1; q &= q - 1;
        const int k = __shfl((int)(u32)pkv, i);
        const float4 ea = ((const float4*)(emb + (size_t)k * CDIM))[lane];
        float p = za.x * ea.x + za.y * ea.y + za.z * ea.z + za.w * ea.w;
#pragma unroll
        for (int s = 1; s < 64; s <<= 1) p += __shfl_xor(p, s);
        const float t1 = znv + enorm2[k];         // fl(zn + en)  — reference chain
        const float d = t1 - 2.0f * p;            // fl(t1 - 2 dot)
        if (d < bdv || (d == bdv && k < bk)) { bdv = d; bk = k; }
    }
    u32 n = ovcnt[t]; if (n > (u32)OVCAP) n = (u32)OVCAP;  // overflow survivors (rare)
    for (u32 i = 0; i < n; ++i) {
        const u64 ov = ovslot[(size_t)t * OVCAP + i];      // wave-uniform broadcast load
        if (!(fdec((u32)(ov >> 32)) <= thr)) continue;
        const int k = (int)(u32)ov;
        const float4 ea = ((const float4*)(emb + (size_t)k * CDIM))[lane];
        float p = za.x * ea.x + za.y * ea.y + za.z * ea.z + za.w * ea.w;
#pragma unroll
        for (int s = 1; s < 64; s <<= 1) p += __shfl_xor(p, s);
        const float t1 = znv + enorm2[k];
        const float d = t1 - 2.0f * p;
        if (d < bdv || (d == bdv && k < bk)) { bdv = d; bk = k; }
    }
    if (lane == 0) {
        idxf[t] = (float)bk;
        dmin[t] = bdv;        // plain coalesced store (NO atomics — r13 lesson)
    }
}

// ---------------- k2: scatter z_q = emb[idx]; last block reduces dmin -> loss scalars ----------
// 1024 threads (100% occupancy at 2 blocks/CU); same per-wave access pattern.
__global__ __launch_bounds__(1024) void k2(const float* __restrict__ emb,
                                           const float* __restrict__ idxf,
                                           const float* __restrict__ dmin,
                                           float* __restrict__ zq,
                                           float* __restrict__ out3,
                                           u32* __restrict__ cnt2) {
    __shared__ int ks[64];
    __shared__ float red[1024];
    __shared__ int lastFlag;
    const int tid = threadIdx.x;
    const int tok0 = blockIdx.x * 64;          // grid = 512
    const int b = tok0 >> 10, hw0 = tok0 & 1023;
    if (tid < 64) ks[tid] = (int)idxf[tok0 + tid];
    __syncthreads();
    const int t4 = (tid & 15) * 4;
    const int ka = ks[t4], kb = ks[t4 + 1], kc = ks[t4 + 2], kd = ks[t4 + 3];
    float* outb = zq + (size_t)b * (CDIM * HW) + hw0 + t4;
    int c = tid >> 4;                          // 0..63
#pragma unroll
    for (int p = 0; p < 4; ++p, c += 64) {
        float4 v;
        v.x = emb[(size_t)ka * CDIM + c];
        v.y = emb[(size_t)kb * CDIM + c];
        v.z = emb[(size_t)kc * CDIM + c];
        v.w = emb[(size_t)kd * CDIM + c];
        *(float4*)(outb + (size_t)c * HW) = v;   // coalesced float4 store
    }
    // last-block election computes the loss (dmin complete: k5 precedes in stream)
    if (tid == 0) lastFlag = (atomicAdd(cnt2, 1u) == 511u) ? 1 : 0;
    __syncthreads();
    if (lastFlag) {
        const float4* d4 = (const float4*)dmin;
        float s = 0.f;
        for (int i = tid; i < NTOK / 4; i += 1024) {
            const float4 v = d4[i];
            s += (v.x + v.y) + (v.z + v.w);
        }
        red[tid] = s;
        __syncthreads();
        for (int o = 512; o > 0; o >>= 1) {
            if (tid < o) red[tid] += red[tid + o];
            __syncthreads();
        }
        if (tid == 0) {
            const float mse = red[0] / (float)NELEM;
            out3[0] = 1.25f * mse;   // loss
            out3[1] = 0.25f * mse;   // commitment_loss
            out3[2] = mse;           // codebook_loss
        }
    }
}

extern "C" void kernel_launch(void* const* d_in, const int* in_sizes, int n_in,
                              void* d_out, int out_size, void* d_ws, size_t ws_size,
                              hipStream_t stream) {
    const float* z   = (const float*)d_in[0];   // [32,256,32,32]
    const float* emb = (const float*)d_in[1];   // [4096,256]
    float* out = (float*)d_out;                 // zq | 3 scalars | idx (as f32)
    char* w = (char*)d_ws;

    float* zn     = (float*)w;                       w += NTOK * 4;
    float* enorm2 = (float*)w;                       w += CB * 4;
    u32*   ovcnt  = (u32*)w;                         w += NTOK * 4;
    float* dmin   = (float*)w;                       w += NTOK * 4;
    u32*   cnt2   = (u32*)w;                         w += 256;
    float* zT     = (float*)w;                       w += (size_t)NTOK * CDIM * 4;
    unsigned short* z_hip = (unsigned short*)w;      w += (size_t)NTOK * CDIM * 2;
    unsigned short* e_hip = (unsigned short*)w;      w += (size_t)CB * CDIM * 2;
    u64*   cand   = (u64*)w;                         w += (size_t)NTOK * 32 * 8;
    u64*   ovslot = (u64*)w;                         w += (size_t)NTOK * OVCAP * 8;
    float* idxf = out + NELEM + 3;

    hipLaunchKernelGGL(prep, dim3(512),       dim3(1024), 0, stream,
                       z, emb, zT, z_hip, zn, ovcnt, enorm2, e_hip, cnt2);
    hipLaunchKernelGGL(p1,  dim3((NTOK / 128) * (CB / 128)), dim3(256), 0, stream,
                       z_hip, e_hip, enorm2, cand, ovcnt, ovslot);
    hipLaunchKernelGGL(k5,  dim3(NTOK / 4),   dim3(256), 0, stream,
                       zT, emb, enorm2, zn, cand, ovcnt, ovslot, idxf, dmin);
    hipLaunchKernelGGL(k2,  dim3(NTOK / 64),  dim3(1024), 0, stream,
                       emb, idxf, dmin, out, out + NELEM, cnt2);
}

// Round 12
// 257.640 us; speedup vs baseline: 1.2517x; 1.1628x over previous
//
#include <hip/hip_runtime.h>

// Problem constants
#define CDIM 256        // token_size (channels)
#define CB   4096       // codebook size
#define HW   1024       // 32*32
#define NTOK 32768      // tokens
#define NELEM 8388608   // 32*256*32*32
#define MARGIN 3.5e-4f  // screen margin; worst-case need ~2e-4 (13-sigma bf16 tail)
#define OVCAP 64        // overflow slots/token; lambda~11.3 -> P(>64) ~ 0 (r12 lesson)

typedef float f32x4 __attribute__((ext_vector_type(4)));
typedef short bf16x8 __attribute__((ext_vector_type(8)));
typedef unsigned int u32;
typedef unsigned long long u64;

__device__ __forceinline__ unsigned short f2bf(float x) {   // RNE fp32->bf16
    u32 b = __float_as_uint(x);
    return (unsigned short)((b + 0x7fffu + ((b >> 16) & 1u)) >> 16);
}
// order-preserving float <-> uint
__device__ __forceinline__ u32 fenc(float f) {
    u32 b = __float_as_uint(f);
    return (b & 0x80000000u) ? ~b : (b | 0x80000000u);
}
__device__ __forceinline__ float fdec(u32 u) {
    return __uint_as_float((u & 0x80000000u) ? (u & 0x7fffffffu) : ~u);
}
__device__ __forceinline__ u64 shfl_xor_u64(u64 v, int s) {
    u32 lo = __shfl_xor((u32)v, s);
    u32 hi = __shfl_xor((u32)(v >> 32), s);
    return ((u64)hi << 32) | lo;
}
// async global->LDS, 16B per lane; lds dest = wave-uniform base + lane*16
__device__ __forceinline__ void gl_lds16(const void* g, void* l) {
    __builtin_amdgcn_global_load_lds(
        (const __attribute__((address_space(1))) u32*)g,
        (__attribute__((address_space(3))) u32*)l, 16, 0, 0);
}

// LESSONS: single-pass barrier-free epilogue, hot-path atomic-free, OVCAP 5x
// headroom, no single-address atomicAdd per wave, RE-CHECK LAUNCH DIMS AFTER
// ANY KERNEL RESHAPE (r8 crash). Latency-bound phases need MAX wave count (r5).
// Never bundle >1 unverified change. LDS staging = async-prefetch engine, not
// a bandwidth cache: gl_lds16 runs off the register dep chain; deleting LDS
// re-serializes loads into it (r10: p1 125->163us, MfmaUtil 23->17.5).
// Ladder: r0 dbuf+swizzle-fix+32x128 waves 205->149; r1 A-direct 149->130;
// r3 counted vmcnt(2)+setprio 130->121. r2 (2 waves/SIMD) FAILED 181.
// r6 XCD swizzle: traffic 4x down, time +2.3 (latency-bound) -> stripped.
// r6 census +3 -> stripped. r5 k5-fusion FAILED 481 (serialized rescore).
// r9 DIAGNOSTIC: prep/k5/k2 each <41.5us; harness 256MiB fills (42us @
// 6.3TB/s) + launch gaps dominate non-p1; p1 is the only big owned lever.
// r10 all-global-B FAILED (above).
// THIS ROUND (r11): restore measured-best r4 config verbatim (258.0us):
// prep 256x1024 T[128][128], p1 = r3 structure (LDS-B dbuf, counted vmcnt,
// setprio, predicated overflow, NO swizzle), k5 1-wave/token, k2 512x1024.

// ---------------- prep: 256 blocks x 1024 threads; p0 + folded k0e ----------------
__global__ __launch_bounds__(1024) void prep(const float* __restrict__ z,
                                             const float* __restrict__ emb,
                                             float* __restrict__ zT,
                                             unsigned short* __restrict__ z_hip,
                                             float* __restrict__ zn,
                                             u32* __restrict__ ovcnt,
                                             float* __restrict__ enorm2,
                                             unsigned short* __restrict__ e_hip,
                                             u32* __restrict__ cnt2) {
    __shared__ float T[128][128];              // 64 KB staging (exactly at static cap)
    const int tid = threadIdx.x;
    const int rg = blockIdx.x;                 // 128-token group, grid = 256
    // ---- folded k0e: 16 codes/block by threads 0..31 (no sync dependency) ----
    // (2 threads/code, linear 128-ch halves; summation order is part of the
    //  reference rounding chain — do not reorder.)
    if (tid < 32) {
        const int code = rg * 16 + (tid >> 1);
        const int cl = code & 127;             // index within 128-code col-group
        const int cgE = code >> 7;
        const int sxzE = (cl >> 1) & 3;        // swizzle key (bank fix, r0)
        float s = 0.f;
#pragma unroll
        for (int kb = 0; kb < 4; ++kb) {
            const int c0 = (tid & 1) * 128 + kb * 32;
            const int kc = c0 >> 5;
            __align__(16) unsigned short tmp[32];
#pragma unroll
            for (int q = 0; q < 8; ++q) {
                float4 v = *(const float4*)(emb + (size_t)code * CDIM + c0 + 4 * q);
                s += v.x * v.x + v.y * v.y + v.z * v.z + v.w * v.w;
                tmp[4 * q + 0] = f2bf(v.x); tmp[4 * q + 1] = f2bf(v.y);
                tmp[4 * q + 2] = f2bf(v.z); tmp[4 * q + 3] = f2bf(v.w);
            }
            uint4* dst4 = (uint4*)(e_hip + (((size_t)(cgE * 8 + kc) * 128 + cl) * 32));
#pragma unroll
            for (int q = 0; q < 4; ++q)
                dst4[q ^ sxzE] = *(uint4*)&tmp[8 * q];   // XOR-swizzled quads
        }
        s += __shfl_xor(s, 1);
        if ((tid & 1) == 0) enorm2[code] = s;
        if (rg == 0 && tid == 0) *cnt2 = 0u;   // k2 last-block election counter
    }
    // ---- p0 role: transpose z -> zT fp32 + packed/swizzled bf16 z + zn/ovcnt ----
    const int b = rg >> 3, hw0 = (rg * 128) & 1023;
    const float* zb = z + (size_t)b * (CDIM * HW) + hw0;
    const int tt = tid & 127;                  // token within group
    const int kcl = (tid >> 7) & 3;            // kc chunk within 128-ch mega-chunk
    const int hbit = tid >> 9;                 // 16-ch half within chunk
    const int hof = hbit * 16;
    const int q0 = hbit * 2;                   // first z_hip quad handled
    const int sxz = (tt >> 1) & 3;             // swizzle key (bank fix, r0)
    float zacc = 0.f;                          // zn order free: translation-invariant
#pragma unroll
    for (int grp = 0; grp < 2; ++grp) {
        const int c0 = grp * 128;
        __syncthreads();                       // T free (prev pack readers done)
#pragma unroll
        for (int p = 0; p < 16; ++p) {
            const int c = p * 8 + (tid >> 7);
            T[c][tid & 127] = zb[(size_t)(c0 + c) * HW + (tid & 127)];
        }
        __syncthreads();
        const int kc = grp * 4 + kcl;
        const int cb = kcl * 32 + hof;         // channel base within mega-chunk
        float* dstT = zT + (size_t)(rg * 128 + tt) * CDIM + c0 + cb;
        __align__(16) unsigned short us[16];
#pragma unroll
        for (int q = 0; q < 4; ++q) {
            float4 v;
            v.x = T[cb + 4 * q + 0][tt]; v.y = T[cb + 4 * q + 1][tt];
            v.z = T[cb + 4 * q + 2][tt]; v.w = T[cb + 4 * q + 3][tt];
            ((float4*)dstT)[q] = v;
            zacc += v.x * v.x + v.y * v.y + v.z * v.z + v.w * v.w;
            us[4 * q + 0] = f2bf(v.x); us[4 * q + 1] = f2bf(v.y);
            us[4 * q + 2] = f2bf(v.z); us[4 * q + 3] = f2bf(v.w);
        }
        uint4* d4 = (uint4*)(z_hip + (((size_t)(rg * 8 + kc) * 128 + tt) * 32));
        d4[q0 ^ sxz]       = *(uint4*)&us[0];   // XOR-swizzled quads
        d4[(q0 + 1) ^ sxz] = *(uint4*)&us[8];
    }
    // ---- zn: reduce 8 role-partials per token via T-overlay ----
    __syncthreads();                           // pack reads of T done
    float* zp = &T[0][0];
    zp[(tid >> 7) * 128 + tt] = zacc;
    __syncthreads();
    if (tid < 128) {
        float s = 0.f;
#pragma unroll
        for (int r = 0; r < 8; ++r) s += zp[r * 128 + tid];
        zn[rg * 128 + tid] = s;
        ovcnt[rg * 128 + tid] = 0u;
    }
}

// Tile: 128 tokens x 128 codes, K=256 in 8 chunks of 32; B double-buffered in
// LDS (16KB), A DIRECT global->VGPR (zero cross-wave reuse -> no LDS round-trip).
// 4 waves; wave w owns rows [w*32, w*32+32) x all 128 cols -> acc[2][8].
// A[m=lane&15][k=quad*8+j]; B as B^T rows (n=lane&15); C: col=lane&15,
// row=quad*4+reg (m89-verified).

// ---------------- p1: bf16 MFMA screen -> per-(token, col-group) min slot + rare overflow ----
// Epilogue: per row, float min over 8 ni + 4-step float butterfly; ballot elects
// lowest-l15 matching lane, which alone builds the u64 (d,k) slot pack. Ties/extras
// d<=min+MARGIN go to the overflow pool (duplicates harmless; k5 rescores).
__global__ __launch_bounds__(256, 4) void p1(const unsigned short* __restrict__ z_hip,
                                             const unsigned short* __restrict__ e_hip,
                                             const float* __restrict__ enorm2,
                                             u64* __restrict__ cand,
                                             u32* __restrict__ ovcnt,
                                             u64* __restrict__ ovslot) {
    __shared__ __align__(16) unsigned short Bs[2][128 * 32];
    const int bid = blockIdx.x;                // grid = 8192
    const int rg = bid >> 5, cg = bid & 31;    // consecutive blocks share A-rows (L2)
    const int tid = threadIdx.x;
    const int w = tid >> 6, lane = tid & 63;
    const int quad = lane >> 4, l15 = lane & 15;
    const int swz = (quad ^ ((l15 >> 1) & 3)) * 8;  // de-swizzle (bank-conflict-free)

    f32x4 acc[2][8];
#pragma unroll
    for (int i = 0; i < 2; ++i)
#pragma unroll
        for (int j = 0; j < 8; ++j)
#pragma unroll
            for (int e = 0; e < 4; ++e) acc[i][j][e] = 0.f;

    const char* gB = (const char*)e_hip + ((size_t)cg << 16) + w * 2048 + lane * 16;
    // A direct-to-reg: per-lane fragment address; same swizzle algebra as the
    // packed store ((row>>1)&3 == (l15>>1)&3 for row = w*32 + mi*16 + l15).
    const char* gA0 = (const char*)z_hip + ((size_t)rg << 16)
                      + (w * 32 + l15) * 64 + swz * 2;
    char* lB = (char*)Bs + w * 2048;           // wave-uniform LDS base (buffer 0)
    // prologue: stage B kc=0, load A frags kc=0
    gl_lds16(gB, lB);           gl_lds16(gB + 1024, lB + 1024);
    gB += 8192;
    bf16x8 af0 = *(const bf16x8*)(gA0);
    bf16x8 af1 = *(const bf16x8*)(gA0 + 1024);
    __syncthreads();                           // full drain before first use
#pragma unroll
    for (int kc = 0; kc < 8; ++kc) {
        const int cur = kc & 1;
        bf16x8 afn0, afn1;
        if (kc < 7) {                          // stage next B tile into other buffer
            char* dB = lB + (cur ^ 1) * 8192;
            gl_lds16(gB, dB);       gl_lds16(gB + 1024, dB + 1024);
            gB += 8192;
            asm volatile("" ::: "memory");     // pin: B-stages are the OLDEST vmem ops
            // prefetch next A fragments (global->reg, stay in flight past barrier)
            const char* gA = gA0 + (size_t)(kc + 1) * 8192;
            afn0 = *(const bf16x8*)(gA);
            afn1 = *(const bf16x8*)(gA + 1024);
        }
        const unsigned short* B0 = Bs[cur];
        __builtin_amdgcn_s_setprio(1);         // T5: favor MFMA-issuing wave
#pragma unroll
        for (int nh = 0; nh < 2; ++nh) {       // 4-at-a-time B frags (VGPR cap)
            bf16x8 bfr[4];
#pragma unroll
            for (int nj = 0; nj < 4; ++nj)
                bfr[nj] = *(const bf16x8*)&B0[((nh * 4 + nj) * 16 + l15) * 32 + swz];
#pragma unroll
            for (int nj = 0; nj < 4; ++nj) {
                acc[0][nh * 4 + nj] = __builtin_amdgcn_mfma_f32_16x16x32_bf16(
                    af0, bfr[nj], acc[0][nh * 4 + nj], 0, 0, 0);
                acc[1][nh * 4 + nj] = __builtin_amdgcn_mfma_f32_16x16x32_bf16(
                    af1, bfr[nj], acc[1][nh * 4 + nj], 0, 0, 0);
            }
        }
        __builtin_amdgcn_s_setprio(0);
        if (kc < 7) {
            af0 = afn0; af1 = afn1;
            // counted wait: retire the 2 B-stages (oldest); A loads stay in flight
            asm volatile("s_waitcnt vmcnt(2)" ::: "memory");
            __builtin_amdgcn_s_barrier();
            asm volatile("" ::: "memory");     // pin next-kc ds_reads below barrier
        }
    }
    // ---- single-pass, barrier-free epilogue (float butterfly + ballot election) ----
    float en[8];
#pragma unroll
    for (int ni = 0; ni < 8; ++ni) en[ni] = enorm2[cg * 128 + ni * 16 + l15];
#pragma unroll
    for (int mi = 0; mi < 2; ++mi) {
#pragma unroll
        for (int r = 0; r < 4; ++r) {
            const int row = w * 32 + mi * 16 + quad * 4 + r;
            const int t = rg * 128 + row;
            float dv[8];
#pragma unroll
            for (int ni = 0; ni < 8; ++ni) dv[ni] = en[ni] - 2.0f * acc[mi][ni][r];
            float m = fminf(fminf(fminf(dv[0], dv[1]), fminf(dv[2], dv[3])),
                            fminf(fminf(dv[4], dv[5]), fminf(dv[6], dv[7])));
            m = fminf(m, __shfl_xor(m, 1));
            m = fminf(m, __shfl_xor(m, 2));
            m = fminf(m, __shfl_xor(m, 4));
            m = fminf(m, __shfl_xor(m, 8));        // 16-lane group min (exact bits)
            u32 myni = 8u;
#pragma unroll
            for (int ni = 7; ni >= 0; --ni)
                if (dv[ni] == m) myni = (u32)ni;   // lowest matching ni
            const unsigned long long bal = __ballot(myni < 8u);
            const int sl = __ffs((u32)((bal >> (quad << 4)) & 0xFFFFu)) - 1;
            if (l15 == sl) {                        // elected lane stores the slot
                const u32 k = (u32)(cg * 128 + (int)myni * 16 + l15);
                cand[((size_t)t << 5) + cg] = ((u64)fenc(m) << 32) | k;
            }
            const float thr = m + MARGIN;
#pragma unroll
            for (int ni = 0; ni < 8; ++ni) {        // rare-path extras (execz-cheap)
                if (dv[ni] <= thr && !(l15 == sl && ni == (int)myni)) {
                    const u32 k = (u32)(cg * 128 + ni * 16 + l15);
                    const u32 pos = atomicAdd(&ovcnt[t], 1u);
                    if (pos < (u32)OVCAP)
                        ovslot[(size_t)t * OVCAP + pos] = ((u64)fenc(dv[ni]) << 32) | k;
                }
            }
        }
    }
}

// ---------------- k5: gmin from 32 slots, filter, exact fp32 rescore; dmin via plain store ----
// 1 wave per token (32768 waves) — latency-bound phase at MAX parallelism (r5 lesson).
__global__ __launch_bounds__(256) void k5(const float* __restrict__ zT,
                                          const float* __restrict__ emb,
                                          const float* __restrict__ enorm2,
                                          const float* __restrict__ zn,
                                          const u64* __restrict__ cand,
                                          const u32* __restrict__ ovcnt,
                                          const u64* __restrict__ ovslot,
                                          float* __restrict__ idxf,
                                          float* __restrict__ dmin) {
    const int t = (blockIdx.x * 256 + threadIdx.x) >> 6;   // wave per token, grid = 8192
    const int lane = threadIdx.x & 63;
    const u64 pkv = cand[((size_t)t << 5) + (lane & 31)];  // 32 slots, dup across halves
    u64 g = pkv;
#pragma unroll
    for (int s = 1; s < 32; s <<= 1) {                     // 5-step min within each half
        const u64 o = shfl_xor_u64(g, s);
        g = o < g ? o : g;
    }
    const float thr = fdec((u32)(g >> 32)) + MARGIN;       // gmin + MARGIN
    const float4 za = ((const float4*)(zT + (size_t)t * CDIM))[lane];
    const float znv = zn[t];
    float bdv = 1e30f; int bk = 0x7fffffff;
    unsigned long long q = __ballot(fdec((u32)(pkv >> 32)) <= thr)
                           & 0xFFFFFFFFull;                // low half only (no dups)
    while (q) {
        const int i = __ffsll(q) - 1; q &= q - 1;
        const int k = __shfl((int)(u32)pkv, i);
        const float4 ea = ((const float4*)(emb + (size_t)k * CDIM))[lane];
        float p = za.x * ea.x + za.y * ea.y + za.z * ea.z + za.w * ea.w;
#pragma unroll
        for (int s = 1; s < 64; s <<= 1) p += __shfl_xor(p, s);
        const float t1 = znv + enorm2[k];         // fl(zn + en)  — reference chain
        const float d = t1 - 2.0f * p;            // fl(t1 - 2 dot)
        if (d < bdv || (d == bdv && k < bk)) { bdv = d; bk = k; }
    }
    u32 n = ovcnt[t]; if (n > (u32)OVCAP) n = (u32)OVCAP;  // overflow survivors (rare)
    for (u32 i = 0; i < n; ++i) {
        const u64 ov = ovslot[(size_t)t * OVCAP + i];      // wave-uniform broadcast load
        if (!(fdec((u32)(ov >> 32)) <= thr)) continue;
        const int k = (int)(u32)ov;
        const float4 ea = ((const float4*)(emb + (size_t)k * CDIM))[lane];
        float p = za.x * ea.x + za.y * ea.y + za.z * ea.z + za.w * ea.w;
#pragma unroll
        for (int s = 1; s < 64; s <<= 1) p += __shfl_xor(p, s);
        const float t1 = znv + enorm2[k];
        const float d = t1 - 2.0f * p;
        if (d < bdv || (d == bdv && k < bk)) { bdv = d; bk = k; }
    }
    if (lane == 0) {
        idxf[t] = (float)bk;
        dmin[t] = bdv;        // plain coalesced store (NO atomics — r13 lesson)
    }
}

// ---------------- k2: scatter z_q = emb[idx]; last block reduces dmin -> loss scalars ----------
// 1024 threads (100% occupancy at 2 blocks/CU); same per-wave access pattern.
__global__ __launch_bounds__(1024) void k2(const float* __restrict__ emb,
                                           const float* __restrict__ idxf,
                                           const float* __restrict__ dmin,
                                           float* __restrict__ zq,
                                           float* __restrict__ out3,
                                           u32* __restrict__ cnt2) {
    __shared__ int ks[64];
    __shared__ float red[1024];
    __shared__ int lastFlag;
    const int tid = threadIdx.x;
    const int tok0 = blockIdx.x * 64;          // grid = 512
    const int b = tok0 >> 10, hw0 = tok0 & 1023;
    if (tid < 64) ks[tid] = (int)idxf[tok0 + tid];
    __syncthreads();
    const int t4 = (tid & 15) * 4;
    const int ka = ks[t4], kb = ks[t4 + 1], kc = ks[t4 + 2], kd = ks[t4 + 3];
    float* outb = zq + (size_t)b * (CDIM * HW) + hw0 + t4;
    int c = tid >> 4;                          // 0..63
#pragma unroll
    for (int p = 0; p < 4; ++p, c += 64) {
        float4 v;
        v.x = emb[(size_t)ka * CDIM + c];
        v.y = emb[(size_t)kb * CDIM + c];
        v.z = emb[(size_t)kc * CDIM + c];
        v.w = emb[(size_t)kd * CDIM + c];
        *(float4*)(outb + (size_t)c * HW) = v;   // coalesced float4 store
    }
    // last-block election computes the loss (dmin complete: k5 precedes in stream)
    if (tid == 0) lastFlag = (atomicAdd(cnt2, 1u) == 511u) ? 1 : 0;
    __syncthreads();
    if (lastFlag) {
        const float4* d4 = (const float4*)dmin;
        float s = 0.f;
        for (int i = tid; i < NTOK / 4; i += 1024) {
            const float4 v = d4[i];
            s += (v.x + v.y) + (v.z + v.w);
        }
        red[tid] = s;
        __syncthreads();
        for (int o = 512; o > 0; o >>= 1) {
            if (tid < o) red[tid] += red[tid + o];
            __syncthreads();
        }
        if (tid == 0) {
            const float mse = red[0] / (float)NELEM;
            out3[0] = 1.25f * mse;   // loss
            out3[1] = 0.25f * mse;   // commitment_loss
            out3[2] = mse;           // codebook_loss
        }
    }
}

extern "C" void kernel_launch(void* const* d_in, const int* in_sizes, int n_in,
                              void* d_out, int out_size, void* d_ws, size_t ws_size,
                              hipStream_t stream) {
    const float* z   = (const float*)d_in[0];   // [32,256,32,32]
    const float* emb = (const float*)d_in[1];   // [4096,256]
    float* out = (float*)d_out;                 // zq | 3 scalars | idx (as f32)
    char* w = (char*)d_ws;

    float* zn     = (float*)w;                       w += NTOK * 4;
    float* enorm2 = (float*)w;                       w += CB * 4;
    u32*   ovcnt  = (u32*)w;                         w += NTOK * 4;
    float* dmin   = (float*)w;                       w += NTOK * 4;
    u32*   cnt2   = (u32*)w;                         w += 256;
    float* zT     = (float*)w;                       w += (size_t)NTOK * CDIM * 4;
    unsigned short* z_hip = (unsigned short*)w;      w += (size_t)NTOK * CDIM * 2;
    unsigned short* e_hip = (unsigned short*)w;      w += (size_t)CB * CDIM * 2;
    u64*   cand   = (u64*)w;                         w += (size_t)NTOK * 32 * 8;
    u64*   ovslot = (u64*)w;                         w += (size_t)NTOK * OVCAP * 8;
    float* idxf = out + NELEM + 3;

    hipLaunchKernelGGL(prep, dim3(256),       dim3(1024), 0, stream,
                       z, emb, zT, z_hip, zn, ovcnt, enorm2, e_hip, cnt2);
    hipLaunchKernelGGL(p1,  dim3((NTOK / 128) * (CB / 128)), dim3(256), 0, stream,
                       z_hip, e_hip, enorm2, cand, ovcnt, ovslot);
    hipLaunchKernelGGL(k5,  dim3(NTOK / 4),   dim3(256), 0, stream,
                       zT, emb, enorm2, zn, cand, ovcnt, ovslot, idxf, dmin);
    hipLaunchKernelGGL(k2,  dim3(NTOK / 64),  dim3(1024), 0, stream,
                       emb, idxf, dmin, out, out + NELEM, cnt2);
}